// Round 9
// baseline (469.496 us; speedup 1.0000x reference)
//
#include <hip/hip_runtime.h>
#include <hip/hip_bf16.h>

#define NB 128
#define NT 1024
#define ND 512
#define NDA 576   // 512 (memory) + 64 (im2col window, 62 used + 2 zero pad)
#define NQ 1024
#define NA 128
#define NF 32
#define NK 31
#define CT2 16
#define NCH2 (NT / CT2)    // 64
#define ROWB 1152          // bytes per LDS sv row (576 bf16)

typedef __attribute__((ext_vector_type(8))) short short8;
typedef __attribute__((ext_vector_type(4))) float f32x4;
typedef __attribute__((ext_vector_type(4))) unsigned int u32x4;
typedef __attribute__((ext_vector_type(2))) unsigned int u32x2;

__device__ __forceinline__ unsigned short f2bf(float f) {
  unsigned int u = __float_as_uint(f);
  u += 0x7fffu + ((u >> 16) & 1u);   // RNE; inputs are finite
  return (unsigned short)(u >> 16);
}
__device__ __forceinline__ unsigned int cvt_pk_bf16(float lo, float hi) {
  unsigned int r;
  asm("v_cvt_pk_bf16_f32 %0, %1, %2" : "=v"(r) : "v"(lo), "v"(hi));
  return r;
}
__device__ __forceinline__ float bf2f(unsigned short u) {
  return __uint_as_float((unsigned int)u << 16);
}
__device__ __forceinline__ float fast_tanh(float x) {
  const float e = __expf(2.f * x);
  return 1.f - 2.f / (e + 1.f);
}
// wt3 packed layout: per (col-tile ct = a>>4, kf = d>>5) a 1KB block,
// lane (lhi = (d>>3)&3, llo = a&15) holds 8 bf16 along k.
__device__ __forceinline__ int wt3_off(int a, int d) {
  return (((a >> 4) * 18 + (d >> 5)) << 9) + (((d >> 3) & 3) << 7) +
         ((a & 15) << 3) + (d & 7);
}

// ---------------------------------------------------------------------------
// Prep: pq partials (0..511), Wm^T -> wt3 (512..575), W2 = ck@Wloc (576..583)
// ---------------------------------------------------------------------------
__global__ __launch_bounds__(256) void lsa_prep(
    const float* __restrict__ query, const float* __restrict__ wq,
    const float* __restrict__ wm, const float* __restrict__ ck,
    const float* __restrict__ wloc,
    float* __restrict__ pq_part, unsigned short* __restrict__ wt3)
{
  const int bid = blockIdx.x;
  const int tid = threadIdx.x;
  if (bid < 512) {
    __shared__ float qs[256];
    __shared__ float red[256];
    const int b = bid >> 2;
    const int qg = bid & 3;
    qs[tid] = query[(size_t)b * NQ + qg * 256 + tid];
    __syncthreads();
    const int a = tid & 127;
    const int h = tid >> 7;
    const float* wqp = wq + (size_t)(qg * 256 + h * 128) * NA + a;
    float acc = 0.f;
#pragma unroll 8
    for (int qi = 0; qi < 128; ++qi)
      acc += qs[h * 128 + qi] * wqp[(size_t)qi * NA];
    red[tid] = acc;
    __syncthreads();
    if (h == 0) pq_part[((size_t)b * 4 + qg) * NA + a] = red[a] + red[128 + a];
  } else if (bid < 576) {
    const int blk = bid - 512;   // 0..63, 8 d-rows each
    for (int i = blk * 1024 + tid; i < blk * 1024 + 1024; i += 256) {
      const int dd = i >> 7, aa = i & 127;
      wt3[wt3_off(aa, dd)] = f2bf(wm[(size_t)dd * NA + aa]);
    }
  } else {
    // W2[w][a] = sum_f ck[k][ch][f]*wloc[f][a], w = 2k+ch; w=62,63 -> 0
    __shared__ float wl_s[NF * NA];
    __shared__ float ck_s[NK * 2 * NF];
    const int blk = bid - 576;   // 0..7
    for (int i = tid; i < NF * NA; i += 256) wl_s[i] = wloc[i];
    for (int i = tid; i < NK * 2 * NF; i += 256) ck_s[i] = ck[i];
    __syncthreads();
    const int a = tid & 127;
    const int h = tid >> 7;
#pragma unroll
    for (int wi = 0; wi < 4; ++wi) {
      const int w = blk * 8 + h * 4 + wi;
      float acc = 0.f;
      if (w < 62) {
        const int k = w >> 1, ch = w & 1;
#pragma unroll
        for (int f = 0; f < NF; ++f)
          acc += ck_s[k * 64 + ch * 32 + f] * wl_s[f * NA + a];
      }
      wt3[wt3_off(a, 512 + w)] = f2bf(acc);
    }
  }
}

// ---------------------------------------------------------------------------
// Main: one (b, 16-row chunk) per 256-thread block; 8 blocks/CU.
// stage -> GEMM -> exp (no max needed: |score| <= sum|v| ~ 9) -> partial
// context; last block per batch (atomic counter) finalizes ctx/attn/cum.
// ---------------------------------------------------------------------------
__global__ __launch_bounds__(256, 8) void lsa_main(
    const float* __restrict__ memory, const int* __restrict__ msl,
    const float* __restrict__ prev, const float* __restrict__ cum,
    const float* __restrict__ pq_part, const float* __restrict__ v_g,
    const unsigned short* __restrict__ wt3,
    float* __restrict__ score_g, float* __restrict__ pl_g,
    float* __restrict__ pctx_g, int* __restrict__ ctr,
    float* __restrict__ out)
{
  const int bid = blockIdx.x;
  const int b = bid >> 6;
  const int ci = bid & 63;
  const int t0 = ci * CT2;
  const int len = msl[b];
  if (t0 >= len) return;                 // fully-masked chunk: never counted
  const int nck = (len + CT2 - 1) >> 4;  // # contributing blocks for batch b
  const int nvalid = min(CT2, len - t0);
  const int tid = threadIdx.x;
  const int wid = tid >> 6;              // 0..3
  const int lane = tid & 63;

  __shared__ __align__(16) unsigned short sv[CT2 * NDA];  // 18 KB
  __shared__ float score2[4][CT2];
  __shared__ float shL;
  __shared__ int lastFlag;

  // ---- stage values -> bf16 LDS (swizzled); loads hoisted ahead of cvt ----
  {
    const int r = tid >> 4;        // 0..15
    const int j = tid & 15;
    const float* src = memory + ((size_t)b * NT + (t0 + r)) * ND + j * 8;
    const f32x4 y0 = *(const f32x4*)(src);
    const f32x4 y1 = *(const f32x4*)(src + 4);
    const f32x4 y2 = *(const f32x4*)(src + 128);
    const f32x4 y3 = *(const f32x4*)(src + 132);
    const f32x4 y4 = *(const f32x4*)(src + 256);
    const f32x4 y5 = *(const f32x4*)(src + 260);
    const f32x4 y6 = *(const f32x4*)(src + 384);
    const f32x4 y7 = *(const f32x4*)(src + 388);
    char* svb = (char*)sv + r * ROWB;
    const int sw = (r & 7) << 4;
    u32x4 pk;
    pk[0] = cvt_pk_bf16(y0[0], y0[1]); pk[1] = cvt_pk_bf16(y0[2], y0[3]);
    pk[2] = cvt_pk_bf16(y1[0], y1[1]); pk[3] = cvt_pk_bf16(y1[2], y1[3]);
    *(u32x4*)(svb + ((j * 16) ^ sw)) = pk;
    pk[0] = cvt_pk_bf16(y2[0], y2[1]); pk[1] = cvt_pk_bf16(y2[2], y2[3]);
    pk[2] = cvt_pk_bf16(y3[0], y3[1]); pk[3] = cvt_pk_bf16(y3[2], y3[3]);
    *(u32x4*)(svb + ((j * 16 + 256) ^ sw)) = pk;
    pk[0] = cvt_pk_bf16(y4[0], y4[1]); pk[1] = cvt_pk_bf16(y4[2], y4[3]);
    pk[2] = cvt_pk_bf16(y5[0], y5[1]); pk[3] = cvt_pk_bf16(y5[2], y5[3]);
    *(u32x4*)(svb + ((j * 16 + 512) ^ sw)) = pk;
    pk[0] = cvt_pk_bf16(y6[0], y6[1]); pk[1] = cvt_pk_bf16(y6[2], y6[3]);
    pk[2] = cvt_pk_bf16(y7[0], y7[1]); pk[3] = cvt_pk_bf16(y7[2], y7[3]);
    *(u32x4*)(svb + ((j * 16 + 768) ^ sw)) = pk;
  }
  // ---- im2col window into cols 512..575 ----
  {
    const int t = tid >> 4;
    const int w0 = (tid & 15) * 4;
    float xv[4];
#pragma unroll
    for (int i = 0; i < 4; ++i) {
      const int w = w0 + i;
      xv[i] = 0.f;
      if (w < 62) {
        const int t3 = t0 - 15 + (w >> 1) + t;
        if (t3 >= 0 && t3 < NT)
          xv[i] = (w & 1) ? cum[(size_t)b * NT + t3] : prev[(size_t)b * NT + t3];
      }
    }
    u32x2 pk;
    pk[0] = cvt_pk_bf16(xv[0], xv[1]);
    pk[1] = cvt_pk_bf16(xv[2], xv[3]);
    *(u32x2*)((char*)sv + t * ROWB + ((1024 + w0 * 2) ^ ((t & 7) << 4))) = pk;
  }
  __syncthreads();

  // ---- GEMM: 16(t) x 32 cols/wave x 576(k); B coalesced from L2 ----
  const int llo = lane & 15, lhi = lane >> 4;
  const int c0 = wid * 32 + llo;         // columns c0 and c0+16
  float esc;
  {
    const unsigned short* bbase = wt3 + ((size_t)wid * 36) * 512 + lane * 8;
    const char* ab = (const char*)sv + llo * ROWB;
    const int asw = (llo & 7) << 4;
    f32x4 acc0 = {0.f, 0.f, 0.f, 0.f};
    f32x4 acc1 = {0.f, 0.f, 0.f, 0.f};
#pragma unroll
    for (int kf = 0; kf < 18; ++kf) {
      const short8 b0 = *(const short8*)(bbase + kf * 512);
      const short8 b1 = *(const short8*)(bbase + kf * 512 + 9216);
      const short8 a = *(const short8*)(ab + ((kf * 64 + lhi * 16) ^ asw));
      acc0 = __builtin_amdgcn_mfma_f32_16x16x32_bf16(a, b0, acc0, 0, 0, 0);
      acc1 = __builtin_amdgcn_mfma_f32_16x16x32_bf16(a, b1, acc1, 0, 0, 0);
    }
    const float* pp = pq_part + (size_t)b * 4 * NA;
    const float pqa = pp[c0] + pp[NA + c0] + pp[2 * NA + c0] + pp[3 * NA + c0];
    const float pqb = pp[c0 + 16] + pp[NA + c0 + 16] + pp[2 * NA + c0 + 16] +
                      pp[3 * NA + c0 + 16];
    const float va = v_g[c0], vb = v_g[c0 + 16];
#pragma unroll
    for (int rg = 0; rg < 4; ++rg) {
      const int r = lhi * 4 + rg;
      float e = fast_tanh(acc0[rg] + pqa) * va + fast_tanh(acc1[rg] + pqb) * vb;
      e += __shfl_xor(e, 1); e += __shfl_xor(e, 2);
      e += __shfl_xor(e, 4); e += __shfl_xor(e, 8);
      if (llo == 0) score2[wid][r] = e;
    }
  }
  __syncthreads();

  // ---- exp weights (no max subtraction; |s| <= sum|v| ~ 9, f32-safe) ----
  {
    const int t = lane & 15;
    const float s = score2[0][t] + score2[1][t] + score2[2][t] + score2[3][t];
    if (wid == 0 && lane < CT2) score_g[(size_t)b * NT + t0 + t] = s;
    esc = (t < nvalid) ? __expf(s) : 0.f;
    float l = esc;
    l += __shfl_xor(l, 1);  l += __shfl_xor(l, 2);
    l += __shfl_xor(l, 4);  l += __shfl_xor(l, 8);
    if (wid == 0 && lane == 0) pl_g[b * NCH2 + ci] = l;
  }

  // ---- partial context: wave covers 128 d's (16 groups of 8) ----
  {
    const int gi = lane >> 2;            // 0..15
    const int sub = lane & 3;            // t-part
    const int g = wid * 16 + gi;         // d-group, d0 = 8g
    const char* svb = (const char*)sv;
    float a8[8];
#pragma unroll
    for (int i = 0; i < 8; ++i) a8[i] = 0.f;
#pragma unroll
    for (int tp = 0; tp < 4; ++tp) {
      const int t2 = tp * 4 + sub;
      const float ee = __shfl(esc, t2);  // lane t2 holds esc for row t2
      const short8 u =
          *(const short8*)(svb + t2 * ROWB + ((g * 16) ^ ((t2 & 7) << 4)));
#pragma unroll
      for (int i = 0; i < 8; ++i) a8[i] += ee * bf2f((unsigned short)u[i]);
    }
#pragma unroll
    for (int i = 0; i < 8; ++i) {
      a8[i] += __shfl_xor(a8[i], 1);
      a8[i] += __shfl_xor(a8[i], 2);
    }
    if (sub == 0) {
      float* dst = pctx_g + ((size_t)(b * NCH2 + ci)) * ND + g * 8;
      const f32x4 lo = {a8[0], a8[1], a8[2], a8[3]};
      const f32x4 hi = {a8[4], a8[5], a8[6], a8[7]};
      *(f32x4*)dst = lo;
      *(f32x4*)(dst + 4) = hi;
    }
  }

  // ---- last-block-per-batch combine ----
  __syncthreads();                       // all global writes issued & drained
  if (tid == 0) {
    __threadfence();                     // flush this XCD's L2 (release)
    const int old = atomicAdd(&ctr[b], 1);
    lastFlag = (old == nck - 1) ? 1 : 0;
  }
  __syncthreads();
  if (lastFlag) {
    __threadfence();                     // acquire
    if (wid == 0) {
      const float pli = (lane < nck) ? pl_g[b * NCH2 + lane] : 0.f;
      float L = pli;
#pragma unroll
      for (int off = 1; off < 64; off <<= 1) L += __shfl_xor(L, off);
      if (lane == 0) shL = L;
    }
    __syncthreads();
    const float Linv = 1.f / shL;
#pragma unroll
    for (int dd = 0; dd < 2; ++dd) {
      const int d = dd * 256 + tid;
      const float* pb = pctx_g + (size_t)b * NCH2 * ND + d;
      float a0 = 0.f, a1 = 0.f, a2 = 0.f, a3 = 0.f;
      int i = 0;
      for (; i + 4 <= nck; i += 4) {
        a0 += pb[(size_t)(i + 0) * ND];
        a1 += pb[(size_t)(i + 1) * ND];
        a2 += pb[(size_t)(i + 2) * ND];
        a3 += pb[(size_t)(i + 3) * ND];
      }
      for (; i < nck; ++i) a0 += pb[(size_t)i * ND];
      out[(size_t)b * ND + d] = (a0 + a1 + a2 + a3) * Linv;
    }
    float* attn_o = out + (size_t)NB * ND;
    float* cum_o = attn_o + (size_t)NB * NT;
#pragma unroll
    for (int it = 0; it < 4; ++it) {
      const int t = it * 256 + tid;
      float w = 0.f;
      if (t < len) w = __expf(score_g[(size_t)b * NT + t]) * Linv;
      attn_o[(size_t)b * NT + t] = w;
      cum_o[(size_t)b * NT + t] = w + cum[(size_t)b * NT + t];
    }
  }
}

extern "C" void kernel_launch(void* const* d_in, const int* in_sizes, int n_in,
                              void* d_out, int out_size, void* d_ws, size_t ws_size,
                              hipStream_t stream) {
  const float* query  = (const float*)d_in[0];
  const float* prev   = (const float*)d_in[1];
  const float* cum    = (const float*)d_in[2];
  const float* memory = (const float*)d_in[3];
  const int*   msl    = (const int*)d_in[4];
  const float* wq     = (const float*)d_in[5];
  const float* wm     = (const float*)d_in[6];
  const float* ck     = (const float*)d_in[7];
  const float* wloc   = (const float*)d_in[8];
  const float* vv     = (const float*)d_in[9];
  float* out = (float*)d_out;

  // workspace layout (floats), ~18 MB
  float* ws = (float*)d_ws;
  float* score_g = ws;                        // 131072
  float* pl_g    = ws + 131072;               // 8192
  float* pctx_g  = ws + 139264;               // 128*64*512 = 4194304
  float* pq_part = ws + 4333568;              // 65536
  unsigned short* wt3 = (unsigned short*)(ws + 4399104);  // 73728 bf16
  int* ctr = (int*)(ws + 4435968);            // 128 ints

  hipMemsetAsync(ctr, 0, NB * sizeof(int), stream);
  lsa_prep<<<584, 256, 0, stream>>>(query, wq, wm, ck, wloc, pq_part, wt3);
  lsa_main<<<NB * NCH2, 256, 0, stream>>>(memory, msl, prev, cum, pq_part, vv,
                                          wt3, score_g, pl_g, pctx_g, ctr, out);
}

// Round 10
// 75.144 us; speedup vs baseline: 6.2480x; 6.2480x over previous
//
#include <hip/hip_runtime.h>
#include <hip/hip_bf16.h>

#define NB 128
#define NT 1024
#define ND 512
#define NDA 576   // 512 (memory) + 64 (im2col window, 62 used + 2 zero pad)
#define NQ 1024
#define NA 128
#define NF 32
#define NK 31
#define CT3 32
#define NCH3 (NT / CT3)    // 32
#define ROWB 1152          // bytes per LDS sv row (576 bf16)

typedef __attribute__((ext_vector_type(8))) short short8;
typedef __attribute__((ext_vector_type(4))) float f32x4;
typedef __attribute__((ext_vector_type(4))) unsigned int u32x4;

__device__ __forceinline__ unsigned short f2bf(float f) {
  unsigned int u = __float_as_uint(f);
  u += 0x7fffu + ((u >> 16) & 1u);   // RNE; inputs are finite
  return (unsigned short)(u >> 16);
}
__device__ __forceinline__ unsigned int cvt_pk_bf16(float lo, float hi) {
  unsigned int r;
  asm("v_cvt_pk_bf16_f32 %0, %1, %2" : "=v"(r) : "v"(lo), "v"(hi));
  return r;
}
__device__ __forceinline__ float bf2f(unsigned short u) {
  return __uint_as_float((unsigned int)u << 16);
}
__device__ __forceinline__ float fast_tanh(float x) {
  const float e = __expf(2.f * x);
  return 1.f - 2.f / (e + 1.f);
}
// wt3 packed layout: per (col-tile ct = a>>4, kf = d>>5) a 1KB block,
// lane (lhi = (d>>3)&3, llo = a&15) holds 8 bf16 along k.
__device__ __forceinline__ int wt3_off(int a, int d) {
  return (((a >> 4) * 18 + (d >> 5)) << 9) + (((d >> 3) & 3) << 7) +
         ((a & 15) << 3) + (d & 7);
}

// ---------------------------------------------------------------------------
// Prep: pq partials (0..511), Wm^T -> wt3 (512..575), W2 = ck@Wloc (576..583)
// ---------------------------------------------------------------------------
__global__ __launch_bounds__(256) void lsa_prep(
    const float* __restrict__ query, const float* __restrict__ wq,
    const float* __restrict__ wm, const float* __restrict__ ck,
    const float* __restrict__ wloc,
    float* __restrict__ pq_part, unsigned short* __restrict__ wt3)
{
  const int bid = blockIdx.x;
  const int tid = threadIdx.x;
  if (bid < 512) {
    __shared__ float qs[256];
    __shared__ float red[256];
    const int b = bid >> 2;
    const int qg = bid & 3;
    qs[tid] = query[(size_t)b * NQ + qg * 256 + tid];
    __syncthreads();
    const int a = tid & 127;
    const int h = tid >> 7;
    const float* wqp = wq + (size_t)(qg * 256 + h * 128) * NA + a;
    float acc = 0.f;
#pragma unroll 8
    for (int qi = 0; qi < 128; ++qi)
      acc += qs[h * 128 + qi] * wqp[(size_t)qi * NA];
    red[tid] = acc;
    __syncthreads();
    if (h == 0) pq_part[((size_t)b * 4 + qg) * NA + a] = red[a] + red[128 + a];
  } else if (bid < 576) {
    const int blk = bid - 512;   // 0..63, 8 d-rows each
    for (int i = blk * 1024 + tid; i < blk * 1024 + 1024; i += 256) {
      const int dd = i >> 7, aa = i & 127;
      wt3[wt3_off(aa, dd)] = f2bf(wm[(size_t)dd * NA + aa]);
    }
  } else {
    // W2[w][a] = sum_f ck[k][ch][f]*wloc[f][a], w = 2k+ch; w=62,63 -> 0
    __shared__ float wl_s[NF * NA];
    __shared__ float ck_s[NK * 2 * NF];
    const int blk = bid - 576;   // 0..7
    for (int i = tid; i < NF * NA; i += 256) wl_s[i] = wloc[i];
    for (int i = tid; i < NK * 2 * NF; i += 256) ck_s[i] = ck[i];
    __syncthreads();
    const int a = tid & 127;
    const int h = tid >> 7;
#pragma unroll
    for (int wi = 0; wi < 4; ++wi) {
      const int w = blk * 8 + h * 4 + wi;
      float acc = 0.f;
      if (w < 62) {
        const int k = w >> 1, ch = w & 1;
#pragma unroll
        for (int f = 0; f < NF; ++f)
          acc += ck_s[k * 64 + ch * 32 + f] * wl_s[f * NA + a];
      }
      wt3[wt3_off(a, 512 + w)] = f2bf(acc);
    }
  }
}

// ---------------------------------------------------------------------------
// Main: one (b, 32-row chunk) per 256-thread block; 4 blocks/CU.
// stage(2 halves) -> GEMM (4 waves x 32 cols x 32 rows; B amortized over
// 32 rows) -> exp (no max: |score| <= sum|v| ~ 9) -> partial context.
// ---------------------------------------------------------------------------
__global__ __launch_bounds__(256, 4) void lsa_main(
    const float* __restrict__ memory, const int* __restrict__ msl,
    const float* __restrict__ prev, const float* __restrict__ cum,
    const float* __restrict__ pq_part, const float* __restrict__ v_g,
    const unsigned short* __restrict__ wt3,
    float* __restrict__ score_g, float* __restrict__ pl_g,
    float* __restrict__ pctx_g)
{
  const int bid = blockIdx.x;
  const int b = bid >> 5;
  const int ci = bid & 31;
  const int t0 = ci * CT3;
  const int len = msl[b];
  if (t0 >= len) return;                 // fully-masked chunk: comb skips it
  const int nvalid = min(CT3, len - t0);
  const int tid = threadIdx.x;
  const int wid = tid >> 6;              // 0..3
  const int lane = tid & 63;

  __shared__ __align__(16) unsigned short sv[CT3 * NDA];  // 36 KB
  __shared__ float score2[4][CT3];

  // ---- stage values -> bf16 LDS (swizzled), 2 halves of 16 rows ----
#pragma unroll
  for (int h = 0; h < 2; ++h) {
    const int r = h * 16 + (tid >> 4);   // row in chunk
    const int j = tid & 15;
    const float* src = memory + ((size_t)b * NT + (t0 + r)) * ND + j * 8;
    const f32x4 y0 = *(const f32x4*)(src);
    const f32x4 y1 = *(const f32x4*)(src + 4);
    const f32x4 y2 = *(const f32x4*)(src + 128);
    const f32x4 y3 = *(const f32x4*)(src + 132);
    const f32x4 y4 = *(const f32x4*)(src + 256);
    const f32x4 y5 = *(const f32x4*)(src + 260);
    const f32x4 y6 = *(const f32x4*)(src + 384);
    const f32x4 y7 = *(const f32x4*)(src + 388);
    char* svb = (char*)sv + r * ROWB;
    const int sw = (r & 7) << 4;
    u32x4 pk;
    pk[0] = cvt_pk_bf16(y0[0], y0[1]); pk[1] = cvt_pk_bf16(y0[2], y0[3]);
    pk[2] = cvt_pk_bf16(y1[0], y1[1]); pk[3] = cvt_pk_bf16(y1[2], y1[3]);
    *(u32x4*)(svb + ((j * 16) ^ sw)) = pk;
    pk[0] = cvt_pk_bf16(y2[0], y2[1]); pk[1] = cvt_pk_bf16(y2[2], y2[3]);
    pk[2] = cvt_pk_bf16(y3[0], y3[1]); pk[3] = cvt_pk_bf16(y3[2], y3[3]);
    *(u32x4*)(svb + ((j * 16 + 256) ^ sw)) = pk;
    pk[0] = cvt_pk_bf16(y4[0], y4[1]); pk[1] = cvt_pk_bf16(y4[2], y4[3]);
    pk[2] = cvt_pk_bf16(y5[0], y5[1]); pk[3] = cvt_pk_bf16(y5[2], y5[3]);
    *(u32x4*)(svb + ((j * 16 + 512) ^ sw)) = pk;
    pk[0] = cvt_pk_bf16(y6[0], y6[1]); pk[1] = cvt_pk_bf16(y6[2], y6[3]);
    pk[2] = cvt_pk_bf16(y7[0], y7[1]); pk[3] = cvt_pk_bf16(y7[2], y7[3]);
    *(u32x4*)(svb + ((j * 16 + 768) ^ sw)) = pk;
  }
  // ---- im2col window into cols 512..575 (one u32x4 per thread) ----
  {
    const int t = tid >> 3;              // 0..31
    const int w0 = (tid & 7) * 8;
    float xv[8];
#pragma unroll
    for (int i = 0; i < 8; ++i) {
      const int w = w0 + i;
      xv[i] = 0.f;
      if (w < 62) {
        const int t3 = t0 - 15 + (w >> 1) + t;
        if (t3 >= 0 && t3 < NT)
          xv[i] = (w & 1) ? cum[(size_t)b * NT + t3] : prev[(size_t)b * NT + t3];
      }
    }
    u32x4 pk;
    pk[0] = cvt_pk_bf16(xv[0], xv[1]); pk[1] = cvt_pk_bf16(xv[2], xv[3]);
    pk[2] = cvt_pk_bf16(xv[4], xv[5]); pk[3] = cvt_pk_bf16(xv[6], xv[7]);
    *(u32x4*)((char*)sv + t * ROWB + ((1024 + (tid & 7) * 16) ^ ((t & 7) << 4))) = pk;
  }
  __syncthreads();

  // ---- GEMM: 32(t) x 32 cols/wave x 576(k); B amortized over 32 rows ----
  const int llo = lane & 15, lhi = lane >> 4;
  const int c0 = wid * 32 + llo;         // columns c0 and c0+16
  float esc;
  {
    const unsigned short* bbase = wt3 + ((size_t)wid * 36) * 512 + lane * 8;
    const char* ab0 = (const char*)sv + llo * ROWB;          // rows 0..15
    const char* ab1 = (const char*)sv + (llo + 16) * ROWB;   // rows 16..31
    const int asw = (llo & 7) << 4;      // same for row llo and llo+16
    f32x4 acc00 = {0.f, 0.f, 0.f, 0.f};
    f32x4 acc01 = {0.f, 0.f, 0.f, 0.f};
    f32x4 acc10 = {0.f, 0.f, 0.f, 0.f};
    f32x4 acc11 = {0.f, 0.f, 0.f, 0.f};
#pragma unroll
    for (int kf = 0; kf < 18; ++kf) {
      const short8 b0 = *(const short8*)(bbase + kf * 512);
      const short8 b1 = *(const short8*)(bbase + kf * 512 + 9216);
      const int bo = (kf * 64 + lhi * 16) ^ asw;
      const short8 a0 = *(const short8*)(ab0 + bo);
      const short8 a1 = *(const short8*)(ab1 + bo);
      acc00 = __builtin_amdgcn_mfma_f32_16x16x32_bf16(a0, b0, acc00, 0, 0, 0);
      acc10 = __builtin_amdgcn_mfma_f32_16x16x32_bf16(a1, b0, acc10, 0, 0, 0);
      acc01 = __builtin_amdgcn_mfma_f32_16x16x32_bf16(a0, b1, acc01, 0, 0, 0);
      acc11 = __builtin_amdgcn_mfma_f32_16x16x32_bf16(a1, b1, acc11, 0, 0, 0);
    }
    const float* pp = pq_part + (size_t)b * 4 * NA;
    const float pqa = pp[c0] + pp[NA + c0] + pp[2 * NA + c0] + pp[3 * NA + c0];
    const float pqb = pp[c0 + 16] + pp[NA + c0 + 16] + pp[2 * NA + c0 + 16] +
                      pp[3 * NA + c0 + 16];
    const float va = v_g[c0], vb = v_g[c0 + 16];
#pragma unroll
    for (int rg = 0; rg < 4; ++rg) {
      const int r = lhi * 4 + rg;
      float e0 = fast_tanh(acc00[rg] + pqa) * va + fast_tanh(acc01[rg] + pqb) * vb;
      float e1 = fast_tanh(acc10[rg] + pqa) * va + fast_tanh(acc11[rg] + pqb) * vb;
      e0 += __shfl_xor(e0, 1); e1 += __shfl_xor(e1, 1);
      e0 += __shfl_xor(e0, 2); e1 += __shfl_xor(e1, 2);
      e0 += __shfl_xor(e0, 4); e1 += __shfl_xor(e1, 4);
      e0 += __shfl_xor(e0, 8); e1 += __shfl_xor(e1, 8);
      if (llo == 0) { score2[wid][r] = e0; score2[wid][r + 16] = e1; }
    }
  }
  __syncthreads();

  // ---- exp weights (no max subtraction; |s| <= sum|v| ~ 9, f32-safe) ----
  {
    const int t = lane & 31;
    const float s = score2[0][t] + score2[1][t] + score2[2][t] + score2[3][t];
    if (wid == 0 && lane < CT3) score_g[(size_t)b * NT + t0 + t] = s;
    esc = (t < nvalid) ? __expf(s) : 0.f;
    float l = esc;
    l += __shfl_xor(l, 1);  l += __shfl_xor(l, 2);  l += __shfl_xor(l, 4);
    l += __shfl_xor(l, 8);  l += __shfl_xor(l, 16);
    if (wid == 0 && lane == 0) pl_g[b * NCH3 + ci] = l;
  }

  // ---- partial context: wave covers 128 d's (16 groups of 8), 8 t-steps ----
  {
    const int gi = lane >> 2;            // 0..15
    const int sub = lane & 3;            // t-part
    const int g = wid * 16 + gi;         // d-group, d0 = 8g
    const char* svb = (const char*)sv;
    float a8[8];
#pragma unroll
    for (int i = 0; i < 8; ++i) a8[i] = 0.f;
#pragma unroll
    for (int tp = 0; tp < 8; ++tp) {
      const int t2 = tp * 4 + sub;
      const float ee = __shfl(esc, t2);  // lane t2 holds esc for row t2
      const short8 u =
          *(const short8*)(svb + t2 * ROWB + ((g * 16) ^ ((t2 & 7) << 4)));
#pragma unroll
      for (int i = 0; i < 8; ++i) a8[i] += ee * bf2f((unsigned short)u[i]);
    }
#pragma unroll
    for (int i = 0; i < 8; ++i) {
      a8[i] += __shfl_xor(a8[i], 1);
      a8[i] += __shfl_xor(a8[i], 2);
    }
    if (sub == 0) {
      float* dst = pctx_g + ((size_t)(b * NCH3 + ci)) * ND + g * 8;
      const f32x4 lo = {a8[0], a8[1], a8[2], a8[3]};
      const f32x4 hi = {a8[4], a8[5], a8[6], a8[7]};
      *(f32x4*)dst = lo;
      *(f32x4*)(dst + 4) = hi;
    }
  }
}

// ---------------------------------------------------------------------------
// Combine: merge <=32 chunk partials per batch (no rescale: same exp scale).
// Grid NB*2: block (b, half) does 256 d's and 512 t's.
// ---------------------------------------------------------------------------
__global__ __launch_bounds__(256) void lsa_comb(
    const int* __restrict__ msl, const float* __restrict__ score_g,
    const float* __restrict__ cum, const float* __restrict__ pl_g,
    const float* __restrict__ pctx_g, float* __restrict__ out)
{
  const int bid = blockIdx.x;
  const int b = bid >> 1;
  const int hf = bid & 1;
  const int tid = threadIdx.x;
  const int len = msl[b];
  const int nck = (len + CT3 - 1) >> 5;   // 16..32
  __shared__ float MLsh;
  if (tid < 64) {
    float L = (tid < nck) ? pl_g[b * NCH3 + tid] : 0.f;
#pragma unroll
    for (int off = 1; off < 32; off <<= 1) L += __shfl_xor(L, off);
    if (tid == 0) MLsh = L;
  }
  __syncthreads();
  const float Linv = 1.f / MLsh;
  {
    const int d = hf * 256 + tid;
    const float* pb = pctx_g + (size_t)b * NCH3 * ND + d;
    float a0 = 0.f, a1 = 0.f, a2 = 0.f, a3 = 0.f;
    int i = 0;
    for (; i + 4 <= nck; i += 4) {
      a0 += pb[(size_t)(i + 0) * ND];
      a1 += pb[(size_t)(i + 1) * ND];
      a2 += pb[(size_t)(i + 2) * ND];
      a3 += pb[(size_t)(i + 3) * ND];
    }
    for (; i < nck; ++i) a0 += pb[(size_t)i * ND];
    out[(size_t)b * ND + d] = (a0 + a1 + a2 + a3) * Linv;
  }
  float* attn_o = out + (size_t)NB * ND;
  float* cum_o = attn_o + (size_t)NB * NT;
#pragma unroll
  for (int it = 0; it < 2; ++it) {
    const int t = hf * 512 + it * 256 + tid;
    float w = 0.f;
    if (t < len) w = __expf(score_g[(size_t)b * NT + t]) * Linv;
    attn_o[(size_t)b * NT + t] = w;
    cum_o[(size_t)b * NT + t] = w + cum[(size_t)b * NT + t];
  }
}

extern "C" void kernel_launch(void* const* d_in, const int* in_sizes, int n_in,
                              void* d_out, int out_size, void* d_ws, size_t ws_size,
                              hipStream_t stream) {
  const float* query  = (const float*)d_in[0];
  const float* prev   = (const float*)d_in[1];
  const float* cum    = (const float*)d_in[2];
  const float* memory = (const float*)d_in[3];
  const int*   msl    = (const int*)d_in[4];
  const float* wq     = (const float*)d_in[5];
  const float* wm     = (const float*)d_in[6];
  const float* ck     = (const float*)d_in[7];
  const float* wloc   = (const float*)d_in[8];
  const float* vv     = (const float*)d_in[9];
  float* out = (float*)d_out;

  // workspace layout (floats), ~9.5 MB
  float* ws = (float*)d_ws;
  float* score_g = ws;                        // 131072
  float* pl_g    = ws + 131072;               // 4096
  float* pctx_g  = ws + 135168;               // 128*32*512 = 2097152
  float* pq_part = ws + 2232320;              // 65536
  unsigned short* wt3 = (unsigned short*)(ws + 2297856);  // 73728 bf16

  lsa_prep<<<584, 256, 0, stream>>>(query, wq, wm, ck, wloc, pq_part, wt3);
  lsa_main<<<NB * NCH3, 256, 0, stream>>>(memory, msl, prev, cum, pq_part, vv,
                                          wt3, score_g, pl_g, pctx_g);
  lsa_comb<<<NB * 2, 256, 0, stream>>>(msl, score_g, cum, pl_g, pctx_g, out);
}

// Round 11
// 74.256 us; speedup vs baseline: 6.3227x; 1.0120x over previous
//
#include <hip/hip_runtime.h>
#include <hip/hip_bf16.h>

#define NB 128
#define NT 1024
#define ND 512
#define NDA 576   // 512 (memory) + 64 (im2col window, 62 used + 2 zero pad)
#define NQ 1024
#define NA 128
#define NF 32
#define NK 31
#define CT3 32
#define NCH3 (NT / CT3)    // 32
#define ROWB 1152          // bytes per LDS sv row (576 bf16)

typedef __attribute__((ext_vector_type(8))) short short8;
typedef __attribute__((ext_vector_type(4))) float f32x4;
typedef __attribute__((ext_vector_type(4))) unsigned int u32x4;

__device__ __forceinline__ unsigned short f2bf(float f) {
  unsigned int u = __float_as_uint(f);
  u += 0x7fffu + ((u >> 16) & 1u);   // RNE; inputs are finite
  return (unsigned short)(u >> 16);
}
__device__ __forceinline__ unsigned int cvt_pk_bf16(float lo, float hi) {
  unsigned int r;
  asm("v_cvt_pk_bf16_f32 %0, %1, %2" : "=v"(r) : "v"(lo), "v"(hi));
  return r;
}
__device__ __forceinline__ float bf2f(unsigned short u) {
  return __uint_as_float((unsigned int)u << 16);
}
__device__ __forceinline__ float fast_tanh(float x) {
  const float e = __expf(2.f * x);
  return 1.f - 2.f / (e + 1.f);
}
// wt3 packed layout: per (col-tile ct = a>>4, kf = d>>5) a 1KB block,
// lane (lhi = (d>>3)&3, llo = a&15) holds 8 bf16 along k.
__device__ __forceinline__ int wt3_off(int a, int d) {
  return (((a >> 4) * 18 + (d >> 5)) << 9) + (((d >> 3) & 3) << 7) +
         ((a & 15) << 3) + (d & 7);
}

// ---------------------------------------------------------------------------
// Prep: pq partials (0..511), Wm^T -> wt3 (512..575), W2 = ck@Wloc (576..583)
// ---------------------------------------------------------------------------
__global__ __launch_bounds__(256) void lsa_prep(
    const float* __restrict__ query, const float* __restrict__ wq,
    const float* __restrict__ wm, const float* __restrict__ ck,
    const float* __restrict__ wloc,
    float* __restrict__ pq_part, unsigned short* __restrict__ wt3)
{
  const int bid = blockIdx.x;
  const int tid = threadIdx.x;
  if (bid < 512) {
    __shared__ float qs[256];
    __shared__ float red[256];
    const int b = bid >> 2;
    const int qg = bid & 3;
    qs[tid] = query[(size_t)b * NQ + qg * 256 + tid];
    __syncthreads();
    const int a = tid & 127;
    const int h = tid >> 7;
    const float* wqp = wq + (size_t)(qg * 256 + h * 128) * NA + a;
    float acc = 0.f;
#pragma unroll 8
    for (int qi = 0; qi < 128; ++qi)
      acc += qs[h * 128 + qi] * wqp[(size_t)qi * NA];
    red[tid] = acc;
    __syncthreads();
    if (h == 0) pq_part[((size_t)b * 4 + qg) * NA + a] = red[a] + red[128 + a];
  } else if (bid < 576) {
    const int blk = bid - 512;   // 0..63, 8 d-rows each
    for (int i = blk * 1024 + tid; i < blk * 1024 + 1024; i += 256) {
      const int dd = i >> 7, aa = i & 127;
      wt3[wt3_off(aa, dd)] = f2bf(wm[(size_t)dd * NA + aa]);
    }
  } else {
    // W2[w][a] = sum_f ck[k][ch][f]*wloc[f][a], w = 2k+ch; w=62,63 -> 0
    __shared__ float wl_s[NF * NA];
    __shared__ float ck_s[NK * 2 * NF];
    const int blk = bid - 576;   // 0..7
    for (int i = tid; i < NF * NA; i += 256) wl_s[i] = wloc[i];
    for (int i = tid; i < NK * 2 * NF; i += 256) ck_s[i] = ck[i];
    __syncthreads();
    const int a = tid & 127;
    const int h = tid >> 7;
#pragma unroll
    for (int wi = 0; wi < 4; ++wi) {
      const int w = blk * 8 + h * 4 + wi;
      float acc = 0.f;
      if (w < 62) {
        const int k = w >> 1, ch = w & 1;
#pragma unroll
        for (int f = 0; f < NF; ++f)
          acc += ck_s[k * 64 + ch * 32 + f] * wl_s[f * NA + a];
      }
      wt3[wt3_off(a, 512 + w)] = f2bf(acc);
    }
  }
}

// ---------------------------------------------------------------------------
// Main: one (b, 32-row chunk) per 256-thread block; 4 blocks/CU.
// stage(2 halves) -> GEMM (4 waves x 32 cols x 32 rows, 6-deep B prefetch)
// -> exp (no max: |score| <= sum|v| ~ 9) -> partial context.
// ---------------------------------------------------------------------------

// 6-deep software pipeline over the 18 k-frags: named regs, no arrays.
#define BLOAD(K) \
  const short8 bA##K = *(const short8*)(bbase + (K) * 512); \
  const short8 bB##K = *(const short8*)(bbase + (K) * 512 + 9216);

#define GSTEP(K) { \
  const int bo = ((K) * 64 + lhi * 16) ^ asw; \
  const short8 a0 = *(const short8*)(ab0 + bo); \
  const short8 a1 = *(const short8*)(ab1 + bo); \
  acc00 = __builtin_amdgcn_mfma_f32_16x16x32_bf16(a0, bA##K, acc00, 0, 0, 0); \
  acc10 = __builtin_amdgcn_mfma_f32_16x16x32_bf16(a1, bA##K, acc10, 0, 0, 0); \
  acc01 = __builtin_amdgcn_mfma_f32_16x16x32_bf16(a0, bB##K, acc01, 0, 0, 0); \
  acc11 = __builtin_amdgcn_mfma_f32_16x16x32_bf16(a1, bB##K, acc11, 0, 0, 0); }

__global__ __launch_bounds__(256, 4) void lsa_main(
    const float* __restrict__ memory, const int* __restrict__ msl,
    const float* __restrict__ prev, const float* __restrict__ cum,
    const float* __restrict__ pq_part, const float* __restrict__ v_g,
    const unsigned short* __restrict__ wt3,
    float* __restrict__ score_g, float* __restrict__ pl_g,
    float* __restrict__ pctx_g)
{
  const int bid = blockIdx.x;
  const int b = bid >> 5;
  const int ci = bid & 31;
  const int t0 = ci * CT3;
  const int len = msl[b];
  if (t0 >= len) return;                 // fully-masked chunk: comb skips it
  const int nvalid = min(CT3, len - t0);
  const int tid = threadIdx.x;
  const int wid = tid >> 6;              // 0..3
  const int lane = tid & 63;

  __shared__ __align__(16) unsigned short sv[CT3 * NDA];  // 36 KB
  __shared__ float score2[4][CT3];

  // ---- stage values -> bf16 LDS (swizzled), 2 halves of 16 rows ----
#pragma unroll
  for (int h = 0; h < 2; ++h) {
    const int r = h * 16 + (tid >> 4);   // row in chunk
    const int j = tid & 15;
    const float* src = memory + ((size_t)b * NT + (t0 + r)) * ND + j * 8;
    const f32x4 y0 = *(const f32x4*)(src);
    const f32x4 y1 = *(const f32x4*)(src + 4);
    const f32x4 y2 = *(const f32x4*)(src + 128);
    const f32x4 y3 = *(const f32x4*)(src + 132);
    const f32x4 y4 = *(const f32x4*)(src + 256);
    const f32x4 y5 = *(const f32x4*)(src + 260);
    const f32x4 y6 = *(const f32x4*)(src + 384);
    const f32x4 y7 = *(const f32x4*)(src + 388);
    char* svb = (char*)sv + r * ROWB;
    const int sw = (r & 7) << 4;
    u32x4 pk;
    pk[0] = cvt_pk_bf16(y0[0], y0[1]); pk[1] = cvt_pk_bf16(y0[2], y0[3]);
    pk[2] = cvt_pk_bf16(y1[0], y1[1]); pk[3] = cvt_pk_bf16(y1[2], y1[3]);
    *(u32x4*)(svb + ((j * 16) ^ sw)) = pk;
    pk[0] = cvt_pk_bf16(y2[0], y2[1]); pk[1] = cvt_pk_bf16(y2[2], y2[3]);
    pk[2] = cvt_pk_bf16(y3[0], y3[1]); pk[3] = cvt_pk_bf16(y3[2], y3[3]);
    *(u32x4*)(svb + ((j * 16 + 256) ^ sw)) = pk;
    pk[0] = cvt_pk_bf16(y4[0], y4[1]); pk[1] = cvt_pk_bf16(y4[2], y4[3]);
    pk[2] = cvt_pk_bf16(y5[0], y5[1]); pk[3] = cvt_pk_bf16(y5[2], y5[3]);
    *(u32x4*)(svb + ((j * 16 + 512) ^ sw)) = pk;
    pk[0] = cvt_pk_bf16(y6[0], y6[1]); pk[1] = cvt_pk_bf16(y6[2], y6[3]);
    pk[2] = cvt_pk_bf16(y7[0], y7[1]); pk[3] = cvt_pk_bf16(y7[2], y7[3]);
    *(u32x4*)(svb + ((j * 16 + 768) ^ sw)) = pk;
  }
  // ---- im2col window into cols 512..575 (one u32x4 per thread) ----
  {
    const int t = tid >> 3;              // 0..31
    const int w0 = (tid & 7) * 8;
    float xv[8];
#pragma unroll
    for (int i = 0; i < 8; ++i) {
      const int w = w0 + i;
      xv[i] = 0.f;
      if (w < 62) {
        const int t3 = t0 - 15 + (w >> 1) + t;
        if (t3 >= 0 && t3 < NT)
          xv[i] = (w & 1) ? cum[(size_t)b * NT + t3] : prev[(size_t)b * NT + t3];
      }
    }
    u32x4 pk;
    pk[0] = cvt_pk_bf16(xv[0], xv[1]); pk[1] = cvt_pk_bf16(xv[2], xv[3]);
    pk[2] = cvt_pk_bf16(xv[4], xv[5]); pk[3] = cvt_pk_bf16(xv[6], xv[7]);
    *(u32x4*)((char*)sv + t * ROWB + ((1024 + (tid & 7) * 16) ^ ((t & 7) << 4))) = pk;
  }
  __syncthreads();

  // ---- GEMM: 32(t) x 32 cols/wave x 576(k); 6-deep B prefetch ----
  const int llo = lane & 15, lhi = lane >> 4;
  const int c0 = wid * 32 + llo;         // columns c0 and c0+16
  float esc;
  {
    const unsigned short* bbase = wt3 + ((size_t)wid * 36) * 512 + lane * 8;
    const char* ab0 = (const char*)sv + llo * ROWB;          // rows 0..15
    const char* ab1 = (const char*)sv + (llo + 16) * ROWB;   // rows 16..31
    const int asw = (llo & 7) << 4;      // same for row llo and llo+16
    // epilogue scalars issued first (oldest in vmem queue, free by epilogue)
    const float* pp = pq_part + (size_t)b * 4 * NA;
    const float pqa = pp[c0] + pp[NA + c0] + pp[2 * NA + c0] + pp[3 * NA + c0];
    const float pqb = pp[c0 + 16] + pp[NA + c0 + 16] + pp[2 * NA + c0 + 16] +
                      pp[3 * NA + c0 + 16];
    const float va = v_g[c0], vb = v_g[c0 + 16];
    f32x4 acc00 = {0.f, 0.f, 0.f, 0.f};
    f32x4 acc01 = {0.f, 0.f, 0.f, 0.f};
    f32x4 acc10 = {0.f, 0.f, 0.f, 0.f};
    f32x4 acc11 = {0.f, 0.f, 0.f, 0.f};
    BLOAD(0) BLOAD(1) BLOAD(2) BLOAD(3) BLOAD(4) BLOAD(5)
    GSTEP(0)  BLOAD(6)
    GSTEP(1)  BLOAD(7)
    GSTEP(2)  BLOAD(8)
    GSTEP(3)  BLOAD(9)
    GSTEP(4)  BLOAD(10)
    GSTEP(5)  BLOAD(11)
    GSTEP(6)  BLOAD(12)
    GSTEP(7)  BLOAD(13)
    GSTEP(8)  BLOAD(14)
    GSTEP(9)  BLOAD(15)
    GSTEP(10) BLOAD(16)
    GSTEP(11) BLOAD(17)
    GSTEP(12) GSTEP(13) GSTEP(14) GSTEP(15) GSTEP(16) GSTEP(17)
#pragma unroll
    for (int rg = 0; rg < 4; ++rg) {
      const int r = lhi * 4 + rg;
      float e0 = fast_tanh(acc00[rg] + pqa) * va + fast_tanh(acc01[rg] + pqb) * vb;
      float e1 = fast_tanh(acc10[rg] + pqa) * va + fast_tanh(acc11[rg] + pqb) * vb;
      e0 += __shfl_xor(e0, 1); e1 += __shfl_xor(e1, 1);
      e0 += __shfl_xor(e0, 2); e1 += __shfl_xor(e1, 2);
      e0 += __shfl_xor(e0, 4); e1 += __shfl_xor(e1, 4);
      e0 += __shfl_xor(e0, 8); e1 += __shfl_xor(e1, 8);
      if (llo == 0) { score2[wid][r] = e0; score2[wid][r + 16] = e1; }
    }
  }
  __syncthreads();

  // ---- exp weights (no max subtraction; |s| <= sum|v| ~ 9, f32-safe) ----
  {
    const int t = lane & 31;
    const float s = score2[0][t] + score2[1][t] + score2[2][t] + score2[3][t];
    if (wid == 0 && lane < CT3) score_g[(size_t)b * NT + t0 + t] = s;
    esc = (t < nvalid) ? __expf(s) : 0.f;
    float l = esc;
    l += __shfl_xor(l, 1);  l += __shfl_xor(l, 2);  l += __shfl_xor(l, 4);
    l += __shfl_xor(l, 8);  l += __shfl_xor(l, 16);
    if (wid == 0 && lane == 0) pl_g[b * NCH3 + ci] = l;
  }

  // ---- partial context: wave covers 128 d's (16 groups of 8), 8 t-steps ----
  {
    const int gi = lane >> 2;            // 0..15
    const int sub = lane & 3;            // t-part
    const int g = wid * 16 + gi;         // d-group, d0 = 8g
    const char* svb = (const char*)sv;
    float a8[8];
#pragma unroll
    for (int i = 0; i < 8; ++i) a8[i] = 0.f;
#pragma unroll
    for (int tp = 0; tp < 8; ++tp) {
      const int t2 = tp * 4 + sub;
      const float ee = __shfl(esc, t2);  // lane t2 holds esc for row t2
      const short8 u =
          *(const short8*)(svb + t2 * ROWB + ((g * 16) ^ ((t2 & 7) << 4)));
#pragma unroll
      for (int i = 0; i < 8; ++i) a8[i] += ee * bf2f((unsigned short)u[i]);
    }
#pragma unroll
    for (int i = 0; i < 8; ++i) {
      a8[i] += __shfl_xor(a8[i], 1);
      a8[i] += __shfl_xor(a8[i], 2);
    }
    if (sub == 0) {
      float* dst = pctx_g + ((size_t)(b * NCH3 + ci)) * ND + g * 8;
      const f32x4 lo = {a8[0], a8[1], a8[2], a8[3]};
      const f32x4 hi = {a8[4], a8[5], a8[6], a8[7]};
      *(f32x4*)dst = lo;
      *(f32x4*)(dst + 4) = hi;
    }
  }
}

// ---------------------------------------------------------------------------
// Combine: merge <=32 chunk partials per batch (no rescale: same exp scale).
// Grid NB*2: block (b, half) does 256 d's and 512 t's.
// ---------------------------------------------------------------------------
__global__ __launch_bounds__(256) void lsa_comb(
    const int* __restrict__ msl, const float* __restrict__ score_g,
    const float* __restrict__ cum, const float* __restrict__ pl_g,
    const float* __restrict__ pctx_g, float* __restrict__ out)
{
  const int bid = blockIdx.x;
  const int b = bid >> 1;
  const int hf = bid & 1;
  const int tid = threadIdx.x;
  const int len = msl[b];
  const int nck = (len + CT3 - 1) >> 5;   // 16..32
  __shared__ float MLsh;
  if (tid < 64) {
    float L = (tid < nck) ? pl_g[b * NCH3 + tid] : 0.f;
#pragma unroll
    for (int off = 1; off < 32; off <<= 1) L += __shfl_xor(L, off);
    if (tid == 0) MLsh = L;
  }
  __syncthreads();
  const float Linv = 1.f / MLsh;
  {
    const int d = hf * 256 + tid;
    const float* pb = pctx_g + (size_t)b * NCH3 * ND + d;
    float a0 = 0.f, a1 = 0.f, a2 = 0.f, a3 = 0.f;
    int i = 0;
    for (; i + 4 <= nck; i += 4) {
      a0 += pb[(size_t)(i + 0) * ND];
      a1 += pb[(size_t)(i + 1) * ND];
      a2 += pb[(size_t)(i + 2) * ND];
      a3 += pb[(size_t)(i + 3) * ND];
    }
    for (; i < nck; ++i) a0 += pb[(size_t)i * ND];
    out[(size_t)b * ND + d] = (a0 + a1 + a2 + a3) * Linv;
  }
  float* attn_o = out + (size_t)NB * ND;
  float* cum_o = attn_o + (size_t)NB * NT;
#pragma unroll
  for (int it = 0; it < 2; ++it) {
    const int t = hf * 512 + it * 256 + tid;
    float w = 0.f;
    if (t < len) w = __expf(score_g[(size_t)b * NT + t]) * Linv;
    attn_o[(size_t)b * NT + t] = w;
    cum_o[(size_t)b * NT + t] = w + cum[(size_t)b * NT + t];
  }
}

extern "C" void kernel_launch(void* const* d_in, const int* in_sizes, int n_in,
                              void* d_out, int out_size, void* d_ws, size_t ws_size,
                              hipStream_t stream) {
  const float* query  = (const float*)d_in[0];
  const float* prev   = (const float*)d_in[1];
  const float* cum    = (const float*)d_in[2];
  const float* memory = (const float*)d_in[3];
  const int*   msl    = (const int*)d_in[4];
  const float* wq     = (const float*)d_in[5];
  const float* wm     = (const float*)d_in[6];
  const float* ck     = (const float*)d_in[7];
  const float* wloc   = (const float*)d_in[8];
  const float* vv     = (const float*)d_in[9];
  float* out = (float*)d_out;

  // workspace layout (floats), ~9.5 MB
  float* ws = (float*)d_ws;
  float* score_g = ws;                        // 131072
  float* pl_g    = ws + 131072;               // 4096
  float* pctx_g  = ws + 135168;               // 128*32*512 = 2097152
  float* pq_part = ws + 2232320;              // 65536
  unsigned short* wt3 = (unsigned short*)(ws + 2297856);  // 73728 bf16

  lsa_prep<<<584, 256, 0, stream>>>(query, wq, wm, ck, wloc, pq_part, wt3);
  lsa_main<<<NB * NCH3, 256, 0, stream>>>(memory, msl, prev, cum, pq_part, vv,
                                          wt3, score_g, pl_g, pctx_g);
  lsa_comb<<<NB * 2, 256, 0, stream>>>(msl, score_g, cum, pl_g, pctx_g, out);
}